// Round 1
// baseline (229.201 us; speedup 1.0000x reference)
//
#include <hip/hip_runtime.h>

// One thread per batch element; quantum state held entirely in registers.
// All state indices are compile-time (templates + full unroll) so CNOT = free
// register rename, rotations = FMA chains. VALU-bound by design.

#define DEVINL __device__ __forceinline__

// ---------------- gates: qubit W of N, state re[]/im[], 1<<N amplitudes ----
// qubit w pairs indices differing in bit (N-1-w).

template<int N, int W>
DEVINL void g_rx(float* re, float* im, float c, float s) {
  constexpr int M = 1 << (N - 1 - W);
  constexpr int SZ = 1 << N;
#pragma unroll
  for (int i = 0; i < SZ; ++i) {
    if (!(i & M)) {
      const int j = i | M;
      float r0 = re[i], i0 = im[i], r1 = re[j], i1 = im[j];
      re[i] = fmaf(c, r0, s * i1);
      im[i] = fmaf(c, i0, -(s * r1));
      re[j] = fmaf(c, r1, s * i0);
      im[j] = fmaf(c, i1, -(s * r0));
    }
  }
}

template<int N, int W>
DEVINL void g_ry(float* re, float* im, float c, float s) {
  constexpr int M = 1 << (N - 1 - W);
  constexpr int SZ = 1 << N;
#pragma unroll
  for (int i = 0; i < SZ; ++i) {
    if (!(i & M)) {
      const int j = i | M;
      float r0 = re[i], i0 = im[i], r1 = re[j], i1 = im[j];
      re[i] = fmaf(c, r0, -(s * r1));
      im[i] = fmaf(c, i0, -(s * i1));
      re[j] = fmaf(c, r1, s * r0);
      im[j] = fmaf(c, i1, s * i0);
    }
  }
}

template<int N, int W>
DEVINL void g_rz(float* re, float* im, float c, float s) {
  // phase e^{-i t/2} on |0>, e^{+i t/2} on |1>; c=cos(t/2), s=sin(t/2)
  constexpr int M = 1 << (N - 1 - W);
  constexpr int SZ = 1 << N;
#pragma unroll
  for (int i = 0; i < SZ; ++i) {
    float r = re[i], m = im[i];
    if (!(i & M)) {
      re[i] = fmaf(c, r, s * m);
      im[i] = fmaf(c, m, -(s * r));
    } else {
      re[i] = fmaf(c, r, -(s * m));
      im[i] = fmaf(c, m, s * r);
    }
  }
}

template<int N, int C, int T>
DEVINL void g_cnot(float* re, float* im) {
  constexpr int CM = 1 << (N - 1 - C);
  constexpr int TM = 1 << (N - 1 - T);
  constexpr int SZ = 1 << N;
#pragma unroll
  for (int i = 0; i < SZ; ++i) {
    if ((i & CM) && !(i & TM)) {
      const int j = i | TM;
      float t;
      t = re[i]; re[i] = re[j]; re[j] = t;
      t = im[i]; im[i] = im[j]; im[j] = t;
    }
  }
}

// ---------------- layers (template recursion over qubit index) -------------

template<int N, int K>
DEVINL void layer_fwd(float* re, float* im, const float* ce, const float* se,
                      const float* cp, const float* sp, const float* cf, const float* sf) {
  if constexpr (K < N) {
    g_rx<N, K>(re, im, ce[K], se[K]);   // RX(eta)
    g_ry<N, K>(re, im, cp[K], sp[K]);   // RY(pt)
    g_rz<N, K>(re, im, cf[K], sf[K]);   // RZ(phi)
    layer_fwd<N, K + 1>(re, im, ce, se, cp, sp, cf, sf);
  }
}

template<int N, int K>
DEVINL void layer_rev(float* re, float* im, const float* ce, const float* se,
                      const float* cp, const float* sp, const float* cf, const float* sf) {
  if constexpr (K < N) {
    g_rz<N, K>(re, im, ce[K], se[K]);   // RZ(eta)
    g_ry<N, K>(re, im, cp[K], sp[K]);   // RY(pt)
    g_rx<N, K>(re, im, cf[K], sf[K]);   // RX(phi)
    layer_rev<N, K + 1>(re, im, ce, se, cp, sp, cf, sf);
  }
}

template<int N, int K>
DEVINL void chain_cnot(float* re, float* im) {
  if constexpr (K < N - 1) {
    g_cnot<N, K, K + 1>(re, im);
    chain_cnot<N, K + 1>(re, im);
  }
}

template<int N, int K>
DEVINL void ry_layer(float* re, float* im, const float* cw, const float* sw) {
  if constexpr (K < N) {
    g_ry<N, K>(re, im, cw[K], sw[K]);
    ry_layer<N, K + 1>(re, im, cw, sw);
  }
}

// ---------------- 4-qubit block: latent=(0,1) trash=(2,3) depth=1 ----------

DEVINL void sim4(const float* pt, const float* eta, const float* phi,
                 const float* cw, const float* sw, float* z0, float* z1) {
  float re[16], im[16];
#pragma unroll
  for (int i = 0; i < 16; ++i) { re[i] = 0.f; im[i] = 0.f; }
  re[0] = 1.f;

  float ce[4], se[4], cp[4], sp[4], cf[4], sf[4];
#pragma unroll
  for (int k = 0; k < 4; ++k) {
    __sincosf(0.5f * eta[k], &se[k], &ce[k]);
    __sincosf(0.5f * pt[k],  &sp[k], &cp[k]);
    __sincosf(0.5f * phi[k], &sf[k], &cf[k]);
  }

  layer_fwd<4, 0>(re, im, ce, se, cp, sp, cf, sf);
  chain_cnot<4, 0>(re, im);
  layer_rev<4, 0>(re, im, ce, se, cp, sp, cf, sf);

  // depth 1: CNOT(t,l) for t in trash, l in latent
  g_cnot<4, 2, 0>(re, im); g_cnot<4, 2, 1>(re, im);
  g_cnot<4, 3, 0>(re, im); g_cnot<4, 3, 1>(re, im);
  ry_layer<4, 0>(re, im, cw, sw);
  g_cnot<4, 0, 2>(re, im); g_cnot<4, 0, 3>(re, im);
  g_cnot<4, 1, 2>(re, im); g_cnot<4, 1, 3>(re, im);

  // <Z> on trash qubits 2 (mask 2) and 3 (mask 1)
  float a0 = 0.f, a1 = 0.f;
#pragma unroll
  for (int i = 0; i < 16; ++i) {
    float p = fmaf(re[i], re[i], im[i] * im[i]);
    a0 += (i & 2) ? -p : p;
    a1 += (i & 1) ? -p : p;
  }
  *z0 = a0; *z1 = a1;
}

// ---------------- 7-qubit block: latent=(0..3) trash=(4,5,6) depth=4 -------

DEVINL void sim7(const float* pt, const float* eta, const float* phi,
                 const float* __restrict__ w, float* z) {
  float re[128], im[128];
#pragma unroll
  for (int i = 0; i < 128; ++i) { re[i] = 0.f; im[i] = 0.f; }
  re[0] = 1.f;

  float ce[7], se[7], cp[7], sp[7], cf[7], sf[7];
#pragma unroll
  for (int k = 0; k < 7; ++k) {
    __sincosf(0.5f * eta[k], &se[k], &ce[k]);
    __sincosf(0.5f * pt[k],  &sp[k], &cp[k]);
    __sincosf(0.5f * phi[k], &sf[k], &cf[k]);
  }

  layer_fwd<7, 0>(re, im, ce, se, cp, sp, cf, sf);
  chain_cnot<7, 0>(re, im);
  layer_rev<7, 0>(re, im, ce, se, cp, sp, cf, sf);

#pragma unroll
  for (int d = 0; d < 4; ++d) {
    // CNOT(t,l): t in (4,5,6), l in (0..3)  [all commute within the set]
    g_cnot<7, 4, 0>(re, im); g_cnot<7, 4, 1>(re, im); g_cnot<7, 4, 2>(re, im); g_cnot<7, 4, 3>(re, im);
    g_cnot<7, 5, 0>(re, im); g_cnot<7, 5, 1>(re, im); g_cnot<7, 5, 2>(re, im); g_cnot<7, 5, 3>(re, im);
    g_cnot<7, 6, 0>(re, im); g_cnot<7, 6, 1>(re, im); g_cnot<7, 6, 2>(re, im); g_cnot<7, 6, 3>(re, im);

    float cw[7], sw[7];
#pragma unroll
    for (int k = 0; k < 7; ++k) __sincosf(0.5f * w[d * 7 + k], &sw[k], &cw[k]);
    ry_layer<7, 0>(re, im, cw, sw);

    // CNOT(l,t): l in (0..3), t in (4,5,6)
    g_cnot<7, 0, 4>(re, im); g_cnot<7, 0, 5>(re, im); g_cnot<7, 0, 6>(re, im);
    g_cnot<7, 1, 4>(re, im); g_cnot<7, 1, 5>(re, im); g_cnot<7, 1, 6>(re, im);
    g_cnot<7, 2, 4>(re, im); g_cnot<7, 2, 5>(re, im); g_cnot<7, 2, 6>(re, im);
    g_cnot<7, 3, 4>(re, im); g_cnot<7, 3, 5>(re, im); g_cnot<7, 3, 6>(re, im);
  }

  // <Z> on trash qubits 4 (mask 4), 5 (mask 2), 6 (mask 1)
  float a0 = 0.f, a1 = 0.f, a2 = 0.f;
#pragma unroll
  for (int i = 0; i < 128; ++i) {
    float p = fmaf(re[i], re[i], im[i] * im[i]);
    a0 += (i & 4) ? -p : p;
    a1 += (i & 2) ? -p : p;
    a2 += (i & 1) ? -p : p;
  }
  z[0] = a0; z[1] = a1; z[2] = a2;
}

// ---------------- kernels ---------------------------------------------------

__global__ void __launch_bounds__(256)
k_abc(const float* __restrict__ x,
      const float* __restrict__ wA, const float* __restrict__ wB, const float* __restrict__ wC,
      float* __restrict__ out, int B) {
  int b = blockIdx.x * blockDim.x + threadIdx.x;
  if (b >= B) return;
  const float* row = x + (size_t)b * 56;
  float pt[4], eta[4], phi[4], cw[4], sw[4], z0, z1;

  { // block A
    constexpr int PT[4] = {5, 4, 35, 34}, ETA[4] = {9, 8, 45, 44}, PHI[4] = {13, 12, 55, 54};
#pragma unroll
    for (int k = 0; k < 4; ++k) { pt[k] = row[PT[k]]; eta[k] = row[ETA[k]]; phi[k] = row[PHI[k]]; }
#pragma unroll
    for (int k = 0; k < 4; ++k) __sincosf(0.5f * wA[k], &sw[k], &cw[k]);
    sim4(pt, eta, phi, cw, sw, &z0, &z1);
    out[(size_t)b * 9 + 0] = z0; out[(size_t)b * 9 + 1] = z1;
  }
  { // block B
    constexpr int PT[4] = {3, 33, 31, 2}, ETA[4] = {7, 43, 41, 6}, PHI[4] = {11, 53, 51, 10};
#pragma unroll
    for (int k = 0; k < 4; ++k) { pt[k] = row[PT[k]]; eta[k] = row[ETA[k]]; phi[k] = row[PHI[k]]; }
#pragma unroll
    for (int k = 0; k < 4; ++k) __sincosf(0.5f * wB[k], &sw[k], &cw[k]);
    sim4(pt, eta, phi, cw, sw, &z0, &z1);
    out[(size_t)b * 9 + 2] = z0; out[(size_t)b * 9 + 3] = z1;
  }
  { // block C
    constexpr int PT[4] = {28, 32, 15, 16}, ETA[4] = {38, 42, 19, 20}, PHI[4] = {48, 52, 23, 24};
#pragma unroll
    for (int k = 0; k < 4; ++k) { pt[k] = row[PT[k]]; eta[k] = row[ETA[k]]; phi[k] = row[PHI[k]]; }
#pragma unroll
    for (int k = 0; k < 4; ++k) __sincosf(0.5f * wC[k], &sw[k], &cw[k]);
    sim4(pt, eta, phi, cw, sw, &z0, &z1);
    out[(size_t)b * 9 + 4] = z0; out[(size_t)b * 9 + 5] = z1;
  }
}

__global__ void __launch_bounds__(256, 1)
k_d(const float* __restrict__ x, const float* __restrict__ wD,
    float* __restrict__ out, int B) {
  int b = blockIdx.x * blockDim.x + threadIdx.x;
  if (b >= B) return;
  const float* row = x + (size_t)b * 56;
  constexpr int PT[7]  = {0, 14, 30, 26, 29, 27, 17};
  constexpr int ETA[7] = {-1, 18, 40, 36, 39, 37, 21};   // -1 -> zeros (None)
  constexpr int PHI[7] = {1, 22, 50, 46, 49, 47, 25};
  float pt[7], eta[7], phi[7], z[3];
#pragma unroll
  for (int k = 0; k < 7; ++k) {
    pt[k]  = row[PT[k]];
    eta[k] = (ETA[k] < 0) ? 0.f : row[ETA[k]];
    phi[k] = row[PHI[k]];
  }
  sim7(pt, eta, phi, wD, z);
  out[(size_t)b * 9 + 6] = z[0];
  out[(size_t)b * 9 + 7] = z[1];
  out[(size_t)b * 9 + 8] = z[2];
}

// ---------------- launch ----------------------------------------------------

extern "C" void kernel_launch(void* const* d_in, const int* in_sizes, int n_in,
                              void* d_out, int out_size, void* d_ws, size_t ws_size,
                              hipStream_t stream) {
  const float* x  = (const float*)d_in[0];
  const float* wA = (const float*)d_in[1];
  const float* wB = (const float*)d_in[2];
  const float* wC = (const float*)d_in[3];
  const float* wD = (const float*)d_in[4];
  float* out = (float*)d_out;
  const int B = in_sizes[0] / 56;
  const int threads = 256;
  const int grid = (B + threads - 1) / threads;
  k_abc<<<grid, threads, 0, stream>>>(x, wA, wB, wC, out, B);
  k_d<<<grid, threads, 0, stream>>>(x, wD, out, B);
}

// Round 2
// 171.924 us; speedup vs baseline: 1.3332x; 1.3332x over previous
//
#include <hip/hip_runtime.h>

// Quantum-circuit batch sim, one thread per element, state in registers as
// float2 (re,im) amplitudes -> uniform 2-vector arithmetic so the backend can
// emit packed v_pk_*_f32 (2 FP32 ops/lane/instr).
//
// Structural cuts vs naive gate-by-gate:
//  - first rotation layer on |0..0> = product state, built by doubling
//    (252 cmuls for 7 qubits vs 21 full-state gate sweeps)
//  - reverse layer RZ*RY*RX merged into ONE 2x2 complex unitary per qubit
//  - CNOTs = compile-time register renames (free)

#define DEVINL __device__ __forceinline__

typedef float v2f __attribute__((ext_vector_type(2)));

DEVINL v2f vsplat(float s) { return (v2f){s, s}; }
// complex multiply: a*b
DEVINL v2f cmul(v2f a, v2f b) {
  v2f t = (v2f){-b.y, b.x};
  return b * vsplat(a.x) + t * vsplat(a.y);
}
// acc + a*b
DEVINL v2f cmadd(v2f acc, v2f a, v2f b) {
  v2f t = (v2f){-b.y, b.x};
  return acc + b * vsplat(a.x) + t * vsplat(a.y);
}

// ---------------- full-state gates (qubit W of N; mask = 1<<(N-1-W)) -------

template<int N, int W>
DEVINL void g_ry(v2f* a, float c, float s) {
  constexpr int M = 1 << (N - 1 - W);
#pragma unroll
  for (int i = 0; i < (1 << N); ++i) {
    if (!(i & M)) {
      const int j = i | M;
      v2f v0 = a[i], v1 = a[j];
      a[i] = vsplat(c) * v0 - vsplat(s) * v1;
      a[j] = vsplat(s) * v0 + vsplat(c) * v1;
    }
  }
}

// general 2x2 complex unitary on qubit W
template<int N, int W>
DEVINL void g_u2(v2f* a, v2f u00, v2f u01, v2f u10, v2f u11) {
  constexpr int M = 1 << (N - 1 - W);
#pragma unroll
  for (int i = 0; i < (1 << N); ++i) {
    if (!(i & M)) {
      const int j = i | M;
      v2f v0 = a[i], v1 = a[j];
      a[i] = cmadd(cmul(u00, v0), u01, v1);
      a[j] = cmadd(cmul(u10, v0), u11, v1);
    }
  }
}

template<int N, int C, int T>
DEVINL void g_cnot(v2f* a) {
  constexpr int CM = 1 << (N - 1 - C);
  constexpr int TM = 1 << (N - 1 - T);
#pragma unroll
  for (int i = 0; i < (1 << N); ++i) {
    if ((i & CM) && !(i & TM)) {
      const int j = i | TM;
      v2f t = a[i]; a[i] = a[j]; a[j] = t;
    }
  }
}

template<int N, int K>
DEVINL void chain_cnot(v2f* a) {
  if constexpr (K < N - 1) {
    g_cnot<N, K, K + 1>(a);
    chain_cnot<N, K + 1>(a);
  }
}

template<int N, int K>
DEVINL void ry_layer(v2f* a, const float* c, const float* s) {
  if constexpr (K < N) {
    g_ry<N, K>(a, c[K], s[K]);
    ry_layer<N, K + 1>(a, c, s);
  }
}

template<int N, int K>
DEVINL void u_layer(v2f* a, const v2f* U00, const v2f* U01, const v2f* U10, const v2f* U11) {
  if constexpr (K < N) {
    g_u2<N, K>(a, U00[K], U01[K], U10[K], U11[K]);
    u_layer<N, K + 1>(a, U00, U01, U10, U11);
  }
}

// ---------------- per-qubit precompute ------------------------------------
// forward: u = Rz(phi)Ry(pt)Rx(eta)|0>
// reverse merged: U = Rx(phi)*Ry(pt)*Rz(eta)  (chronological RZ,RY,RX)
DEVINL void rot_u(float e, float p, float f,
                  v2f& u0, v2f& u1,
                  v2f& U00, v2f& U01, v2f& U10, v2f& U11) {
  float ce, se, cp, sp, cf, sf;
  __sincosf(0.5f * e, &se, &ce);
  __sincosf(0.5f * p, &sp, &cp);
  __sincosf(0.5f * f, &sf, &cf);
  // |0> -RX(e)-> (ce, -i se) -RY(p)-> a0 = cp*ce + i sp*se ; a1 = sp*ce - i cp*se
  // -RZ(f)-> a0 *= (cf - i sf); a1 *= (cf + i sf)
  u0 = cmul((v2f){cf, -sf}, (v2f){cp * ce, sp * se});
  u1 = cmul((v2f){cf, sf}, (v2f){sp * ce, -cp * se});
  // U = RX(f)*RY(p)*RZ(e):
  //   U00 = (cf*cp - i sf*sp)*z    U01 = -(cf*sp + i sf*cp)*conj(z)
  //   U10 = (cf*sp - i sf*cp)*z    U11 = (cf*cp + i sf*sp)*conj(z)
  // where z = e^{-i e/2} = (ce, -se)
  v2f z = (v2f){ce, -se}, zb = (v2f){ce, se};
  U00 = cmul((v2f){cf * cp, -sf * sp}, z);
  v2f t = cmul((v2f){cf * sp, sf * cp}, zb);
  U01 = (v2f){-t.x, -t.y};
  U10 = cmul((v2f){cf * sp, -sf * cp}, z);
  U11 = cmul((v2f){cf * cp, sf * sp}, zb);
}

// product-state build by doubling: a[i] = prod_k u_k[bit_k(i)], q0 = MSB
template<int NQ>
DEVINL void build_product(v2f* a, const v2f* u0, const v2f* u1) {
  a[0] = u0[0];
  a[1] = u1[0];
#pragma unroll
  for (int m = 1; m < NQ; ++m) {
    const int size = 1 << m;
#pragma unroll
    for (int j = size - 1; j >= 0; --j) {
      v2f s = a[j];
      a[2 * j]     = cmul(s, u0[m]);
      a[2 * j + 1] = cmul(s, u1[m]);
    }
  }
}

// ---------------- 4-qubit block: latent=(0,1) trash=(2,3) depth=1 ----------

DEVINL void sim4(const float* pt, const float* eta, const float* phi,
                 const float* cw, const float* sw, float* z0, float* z1) {
  v2f u0[4], u1[4], U00[4], U01[4], U10[4], U11[4];
#pragma unroll
  for (int k = 0; k < 4; ++k)
    rot_u(eta[k], pt[k], phi[k], u0[k], u1[k], U00[k], U01[k], U10[k], U11[k]);

  v2f a[16];
  build_product<4>(a, u0, u1);
  chain_cnot<4, 0>(a);
  u_layer<4, 0>(a, U00, U01, U10, U11);

  g_cnot<4, 2, 0>(a); g_cnot<4, 2, 1>(a);
  g_cnot<4, 3, 0>(a); g_cnot<4, 3, 1>(a);
  ry_layer<4, 0>(a, cw, sw);
  g_cnot<4, 0, 2>(a); g_cnot<4, 0, 3>(a);
  g_cnot<4, 1, 2>(a); g_cnot<4, 1, 3>(a);

  float s0 = 0.f, s1 = 0.f;
#pragma unroll
  for (int i = 0; i < 16; ++i) {
    float p = fmaf(a[i].x, a[i].x, a[i].y * a[i].y);
    s0 += (i & 2) ? -p : p;
    s1 += (i & 1) ? -p : p;
  }
  *z0 = s0; *z1 = s1;
}

// ---------------- 7-qubit block: latent=(0..3) trash=(4,5,6) depth=4 -------

DEVINL void sim7(const float* pt, const float* eta, const float* phi,
                 const float* __restrict__ w, float* zout) {
  v2f u0[7], u1[7], U00[7], U01[7], U10[7], U11[7];
#pragma unroll
  for (int k = 0; k < 7; ++k)
    rot_u(eta[k], pt[k], phi[k], u0[k], u1[k], U00[k], U01[k], U10[k], U11[k]);

  v2f a[128];
  build_product<7>(a, u0, u1);
  chain_cnot<7, 0>(a);
  u_layer<7, 0>(a, U00, U01, U10, U11);

#pragma unroll
  for (int d = 0; d < 4; ++d) {
    g_cnot<7, 4, 0>(a); g_cnot<7, 4, 1>(a); g_cnot<7, 4, 2>(a); g_cnot<7, 4, 3>(a);
    g_cnot<7, 5, 0>(a); g_cnot<7, 5, 1>(a); g_cnot<7, 5, 2>(a); g_cnot<7, 5, 3>(a);
    g_cnot<7, 6, 0>(a); g_cnot<7, 6, 1>(a); g_cnot<7, 6, 2>(a); g_cnot<7, 6, 3>(a);

    float cw[7], sw[7];
#pragma unroll
    for (int k = 0; k < 7; ++k) __sincosf(0.5f * w[d * 7 + k], &sw[k], &cw[k]);
    ry_layer<7, 0>(a, cw, sw);

    g_cnot<7, 0, 4>(a); g_cnot<7, 0, 5>(a); g_cnot<7, 0, 6>(a);
    g_cnot<7, 1, 4>(a); g_cnot<7, 1, 5>(a); g_cnot<7, 1, 6>(a);
    g_cnot<7, 2, 4>(a); g_cnot<7, 2, 5>(a); g_cnot<7, 2, 6>(a);
    g_cnot<7, 3, 4>(a); g_cnot<7, 3, 5>(a); g_cnot<7, 3, 6>(a);
  }

  float s0 = 0.f, s1 = 0.f, s2 = 0.f;
#pragma unroll
  for (int i = 0; i < 128; ++i) {
    float p = fmaf(a[i].x, a[i].x, a[i].y * a[i].y);
    s0 += (i & 4) ? -p : p;
    s1 += (i & 2) ? -p : p;
    s2 += (i & 1) ? -p : p;
  }
  zout[0] = s0; zout[1] = s1; zout[2] = s2;
}

// ---------------- kernels ---------------------------------------------------

__global__ void __launch_bounds__(256)
k_abc(const float* __restrict__ x,
      const float* __restrict__ wA, const float* __restrict__ wB, const float* __restrict__ wC,
      float* __restrict__ out, int B) {
  // stage 256 rows (56 floats each) coalesced into LDS, stride 57 (odd -> no
  // bank conflicts on the later per-thread row gather).
  __shared__ float lds[256 * 57];
  const int tid = threadIdx.x;
  const int base = blockIdx.x * 256;

  if (base + 256 <= B) {
    const float4* x4 = (const float4*)x + (size_t)base * 14;  // 56 floats = 14 float4
#pragma unroll
    for (int i = 0; i < 14; ++i) {
      int f = i * 256 + tid;
      float4 v = x4[f];
      int r = f / 14, c4 = f - r * 14;
      float* dst = &lds[r * 57 + c4 * 4];
      dst[0] = v.x; dst[1] = v.y; dst[2] = v.z; dst[3] = v.w;
    }
  } else {
    int r = base + tid;
    if (r < B)
      for (int c = 0; c < 56; ++c) lds[tid * 57 + c] = x[(size_t)r * 56 + c];
  }
  __syncthreads();

  const int b = base + tid;
  if (b >= B) return;
  const float* row = &lds[tid * 57];

  float pt[4], eta[4], phi[4], cw[4], sw[4], z0, z1;

  { // block A
    constexpr int PT[4] = {5, 4, 35, 34}, ETA[4] = {9, 8, 45, 44}, PHI[4] = {13, 12, 55, 54};
#pragma unroll
    for (int k = 0; k < 4; ++k) { pt[k] = row[PT[k]]; eta[k] = row[ETA[k]]; phi[k] = row[PHI[k]]; }
#pragma unroll
    for (int k = 0; k < 4; ++k) __sincosf(0.5f * wA[k], &sw[k], &cw[k]);
    sim4(pt, eta, phi, cw, sw, &z0, &z1);
    out[(size_t)b * 9 + 0] = z0; out[(size_t)b * 9 + 1] = z1;
  }
  { // block B
    constexpr int PT[4] = {3, 33, 31, 2}, ETA[4] = {7, 43, 41, 6}, PHI[4] = {11, 53, 51, 10};
#pragma unroll
    for (int k = 0; k < 4; ++k) { pt[k] = row[PT[k]]; eta[k] = row[ETA[k]]; phi[k] = row[PHI[k]]; }
#pragma unroll
    for (int k = 0; k < 4; ++k) __sincosf(0.5f * wB[k], &sw[k], &cw[k]);
    sim4(pt, eta, phi, cw, sw, &z0, &z1);
    out[(size_t)b * 9 + 2] = z0; out[(size_t)b * 9 + 3] = z1;
  }
  { // block C
    constexpr int PT[4] = {28, 32, 15, 16}, ETA[4] = {38, 42, 19, 20}, PHI[4] = {48, 52, 23, 24};
#pragma unroll
    for (int k = 0; k < 4; ++k) { pt[k] = row[PT[k]]; eta[k] = row[ETA[k]]; phi[k] = row[PHI[k]]; }
#pragma unroll
    for (int k = 0; k < 4; ++k) __sincosf(0.5f * wC[k], &sw[k], &cw[k]);
    sim4(pt, eta, phi, cw, sw, &z0, &z1);
    out[(size_t)b * 9 + 4] = z0; out[(size_t)b * 9 + 5] = z1;
  }
}

__global__ void __launch_bounds__(256, 1)
k_d(const float* __restrict__ x, const float* __restrict__ wD,
    float* __restrict__ out, int B) {
  const int b = blockIdx.x * blockDim.x + threadIdx.x;
  if (b >= B) return;
  const float* row = x + (size_t)b * 56;
  constexpr int PT[7]  = {0, 14, 30, 26, 29, 27, 17};
  constexpr int ETA[7] = {-1, 18, 40, 36, 39, 37, 21};   // -1 -> zeros (None)
  constexpr int PHI[7] = {1, 22, 50, 46, 49, 47, 25};
  float pt[7], eta[7], phi[7], z[3];
#pragma unroll
  for (int k = 0; k < 7; ++k) {
    pt[k]  = row[PT[k]];
    eta[k] = (ETA[k] < 0) ? 0.f : row[ETA[k]];
    phi[k] = row[PHI[k]];
  }
  sim7(pt, eta, phi, wD, z);
  out[(size_t)b * 9 + 6] = z[0];
  out[(size_t)b * 9 + 7] = z[1];
  out[(size_t)b * 9 + 8] = z[2];
}

// ---------------- launch ----------------------------------------------------

extern "C" void kernel_launch(void* const* d_in, const int* in_sizes, int n_in,
                              void* d_out, int out_size, void* d_ws, size_t ws_size,
                              hipStream_t stream) {
  const float* x  = (const float*)d_in[0];
  const float* wA = (const float*)d_in[1];
  const float* wB = (const float*)d_in[2];
  const float* wC = (const float*)d_in[3];
  const float* wD = (const float*)d_in[4];
  float* out = (float*)d_out;
  const int B = in_sizes[0] / 56;
  const int threads = 256;
  const int grid = (B + threads - 1) / threads;
  k_abc<<<grid, threads, 0, stream>>>(x, wA, wB, wC, out, B);
  k_d<<<grid, threads, 0, stream>>>(x, wD, out, B);
}

// Round 3
// 127.726 us; speedup vs baseline: 1.7945x; 1.3460x over previous
//
#include <hip/hip_runtime.h>
#include <hip/hip_fp16.h>

// Batched quantum-circuit sim, ONE fused kernel, one thread per element.
// State: __half2 (re,im) per amplitude -> 1 VGPR/amplitude, gates via
// v_pk_fma_f16 (2 FLOP/instr). Coefficients precomputed in f32.
// All CNOTs (incl. depth-loop blocks, collapsed to net parity permutations)
// are compile-time register renames. Readout via v_dot2_f32_f16.

#define DEVINL __device__ __forceinline__

typedef _Float16 hv2 __attribute__((ext_vector_type(2)));

struct C2 { __half2 rr, mp; };  // complex const (r,i): rr=(r,r), mp=(-i,+i)

DEVINL C2 mkc(float re, float im) {
  C2 c; c.rr = __floats2half2_rn(re, re); c.mp = __floats2half2_rn(-im, im); return c;
}
DEVINL __half2 mkamp(float re, float im) { return __floats2half2_rn(re, im); }
DEVINL __half2 swap2(__half2 v) { return __lowhigh2highlow(v); }
// (const u) * (amp v):  (r*vr - i*vi, r*vi + i*vr)
DEVINL __half2 cmulc(C2 u, __half2 v) { return __hfma2(u.rr, v, __hmul2(u.mp, swap2(v))); }

DEVINL float ampsq(__half2 v, float acc) {
#if __has_builtin(__builtin_amdgcn_fdot2)
  return __builtin_amdgcn_fdot2(__builtin_bit_cast(hv2, v), __builtin_bit_cast(hv2, v), acc, false);
#else
  float2 f = __half22float2(v);
  return fmaf(f.x, f.x, fmaf(f.y, f.y, acc));
#endif
}

constexpr int parc(int x) { x ^= x >> 4; x ^= x >> 2; x ^= x >> 1; return x & 1; }

struct c32 { float x, y; };
DEVINL c32 cmulf(c32 a, c32 b) { return { a.x*b.x - a.y*b.y, a.x*b.y + a.y*b.x }; }

// ---------------- gates (qubit W of N; mask = 1<<(N-1-W)) -------------------

template<int N, int W>
DEVINL void g_ry(__half2* a, __half2 c2, __half2 s2, __half2 ns2) {
  constexpr int M = 1 << (N - 1 - W);
#pragma unroll
  for (int i = 0; i < (1 << N); ++i) if (!(i & M)) {
    const int j = i | M;
    __half2 v0 = a[i], v1 = a[j];
    a[i] = __hfma2(c2, v0, __hmul2(ns2, v1));
    a[j] = __hfma2(c2, v1, __hmul2(s2, v0));
  }
}

template<int N, int W>
DEVINL void g_u2(__half2* a, C2 u00, C2 u01, C2 u10, C2 u11) {
  constexpr int M = 1 << (N - 1 - W);
#pragma unroll
  for (int i = 0; i < (1 << N); ++i) if (!(i & M)) {
    const int j = i | M;
    __half2 v0 = a[i], v1 = a[j], v0s = swap2(v0), v1s = swap2(v1);
    a[i] = __hfma2(u00.rr, v0, __hfma2(u00.mp, v0s, __hfma2(u01.rr, v1, __hmul2(u01.mp, v1s))));
    a[j] = __hfma2(u10.rr, v0, __hfma2(u10.mp, v0s, __hfma2(u11.rr, v1, __hmul2(u11.mp, v1s))));
  }
}

template<int N, int C, int T>
DEVINL void g_cnot(__half2* a) {
  constexpr int CM = 1 << (N - 1 - C), TM = 1 << (N - 1 - T);
#pragma unroll
  for (int i = 0; i < (1 << N); ++i) if ((i & CM) && !(i & TM)) {
    const int j = i | TM;
    __half2 t = a[i]; a[i] = a[j]; a[j] = t;
  }
}

template<int N, int K>
DEVINL void chain_cnot(__half2* a) {
  if constexpr (K < N - 1) { g_cnot<N, K, K + 1>(a); chain_cnot<N, K + 1>(a); }
}

// ---------------- per-qubit coefficients (f32) ------------------------------
// forward: u = Rz(phi)Ry(pt)Rx(eta)|0>;  reverse merged: U = Rx(phi)Ry(pt)Rz(eta)

DEVINL void mk_u01(float ce, float se, float cp, float sp, float cf, float sf,
                   c32& u0, c32& u1) {
  u0 = cmulf({cf, -sf}, {cp * ce, sp * se});
  u1 = cmulf({cf,  sf}, {sp * ce, -cp * se});
}

DEVINL void mk_U(float ce, float se, float cp, float sp, float cf, float sf,
                 C2& U00, C2& U01, C2& U10, C2& U11) {
  c32 z = {ce, -se}, zb = {ce, se};
  c32 A = cmulf({cf * cp, -sf * sp}, z);
  c32 T = cmulf({cf * sp,  sf * cp}, zb);
  c32 Cc = cmulf({cf * sp, -sf * cp}, z);
  c32 D = cmulf({cf * cp,  sf * sp}, zb);
  U00 = mkc(A.x, A.y); U01 = mkc(-T.x, -T.y); U10 = mkc(Cc.x, Cc.y); U11 = mkc(D.x, D.y);
}

// product state build by doubling (a[0] must be (1,0) on entry)
template<int N, int M>
DEVINL void build_step(__half2* a, const float* ce, const float* se, const float* cp,
                       const float* sp, const float* cf, const float* sf) {
  if constexpr (M < N) {
    c32 u0, u1; mk_u01(ce[M], se[M], cp[M], sp[M], cf[M], sf[M], u0, u1);
    C2 c0 = mkc(u0.x, u0.y), c1 = mkc(u1.x, u1.y);
#pragma unroll
    for (int j = (1 << M) - 1; j >= 0; --j) {
      __half2 s = a[j];
      a[2 * j]     = cmulc(c0, s);
      a[2 * j + 1] = cmulc(c1, s);
    }
    build_step<N, M + 1>(a, ce, se, cp, sp, cf, sf);
  }
}

template<int N, int K>
DEVINL void u_sweep(__half2* a, const float* ce, const float* se, const float* cp,
                    const float* sp, const float* cf, const float* sf) {
  if constexpr (K < N) {
    C2 U00, U01, U10, U11;
    mk_U(ce[K], se[K], cp[K], sp[K], cf[K], sf[K], U00, U01, U10, U11);
    g_u2<N, K>(a, U00, U01, U10, U11);
    u_sweep<N, K + 1>(a, ce, se, cp, sp, cf, sf);
  }
}

template<int N, int K>
DEVINL void ry_sweep(__half2* a, const __half2* c2, const __half2* s2, const __half2* ns2) {
  if constexpr (K < N) {
    g_ry<N, K>(a, c2[K], s2[K], ns2[K]);
    ry_sweep<N, K + 1>(a, c2, s2, ns2);
  }
}

// ---------------- 4-qubit block I: latent=(0,1) trash=(2,3) depth=1 ---------

template<int I>
DEVINL void sim4h(const float* r, const float* __restrict__ w, float* z) {
  constexpr int PT[3][4]  = {{5, 4, 35, 34}, {3, 33, 31, 2}, {28, 32, 15, 16}};
  constexpr int ETA[3][4] = {{9, 8, 45, 44}, {7, 43, 41, 6}, {38, 42, 19, 20}};
  constexpr int PHI[3][4] = {{13, 12, 55, 54}, {11, 53, 51, 10}, {48, 52, 23, 24}};
  float ce[4], se[4], cp[4], sp[4], cf[4], sf[4];
#pragma unroll
  for (int k = 0; k < 4; ++k) {
    __sincosf(0.5f * r[ETA[I][k]], &se[k], &ce[k]);
    __sincosf(0.5f * r[PT[I][k]],  &sp[k], &cp[k]);
    __sincosf(0.5f * r[PHI[I][k]], &sf[k], &cf[k]);
  }
  __half2 a[16];
  a[0] = mkamp(1.f, 0.f);
  build_step<4, 0>(a, ce, se, cp, sp, cf, sf);
  chain_cnot<4, 0>(a);
  u_sweep<4, 0>(a, ce, se, cp, sp, cf, sf);

  // t->l CNOT block == flip q0,q1 (mask 12) iff parity(b2,b3) (i&3)
#pragma unroll
  for (int i = 0; i < 16; ++i)
    if (parc(i & 3) && !(i & 8)) { __half2 t = a[i]; a[i] = a[i ^ 12]; a[i ^ 12] = t; }

  __half2 c2[4], s2[4], ns2[4];
#pragma unroll
  for (int k = 0; k < 4; ++k) {
    float sv, cv; __sincosf(0.5f * w[k], &sv, &cv);
    c2[k] = __floats2half2_rn(cv, cv);
    s2[k] = __floats2half2_rn(sv, sv);
    ns2[k] = __floats2half2_rn(-sv, -sv);
  }
  ry_sweep<4, 0>(a, c2, s2, ns2);

  // l->t CNOT block == flip q2,q3 (mask 3) iff parity(b0,b1) (i&12)
#pragma unroll
  for (int i = 0; i < 16; ++i)
    if (parc(i & 12) && !(i & 2)) { __half2 t = a[i]; a[i] = a[i ^ 3]; a[i ^ 3] = t; }

  float cls[4];
#pragma unroll
  for (int c = 0; c < 4; ++c) cls[c] = 0.f;
#pragma unroll
  for (int i = 0; i < 16; ++i) cls[i & 3] = ampsq(a[i], cls[i & 3]);
  float z0 = 0.f, z1 = 0.f;
#pragma unroll
  for (int c = 0; c < 4; ++c) {
    z0 += (c & 2) ? -cls[c] : cls[c];
    z1 += (c & 1) ? -cls[c] : cls[c];
  }
  z[0] = z0; z[1] = z1;
}

// ---------------- 7-qubit block: latent=(0..3) trash=(4,5,6) depth=4 --------

DEVINL void sim7h(const float* r, const float* __restrict__ wD, float* z) {
  constexpr int PT[7]  = {0, 14, 30, 26, 29, 27, 17};
  constexpr int ETA[7] = {-1, 18, 40, 36, 39, 37, 21};  // -1 -> zeros (None)
  constexpr int PHI[7] = {1, 22, 50, 46, 49, 47, 25};
  float ce[7], se[7], cp[7], sp[7], cf[7], sf[7];
#pragma unroll
  for (int k = 0; k < 7; ++k) {
    float e = (ETA[k] < 0) ? 0.f : r[ETA[k]];
    __sincosf(0.5f * e, &se[k], &ce[k]);
    __sincosf(0.5f * r[PT[k]],  &sp[k], &cp[k]);
    __sincosf(0.5f * r[PHI[k]], &sf[k], &cf[k]);
  }
  __half2 a[128];
  a[0] = mkamp(1.f, 0.f);
  build_step<7, 0>(a, ce, se, cp, sp, cf, sf);
  chain_cnot<7, 0>(a);
  u_sweep<7, 0>(a, ce, se, cp, sp, cf, sf);

  // depth loop kept rolled (#pragma unroll 1): body stays in L1I
#pragma unroll 1
  for (int d = 0; d < 4; ++d) {
    // t->l block == flip q0..q3 (mask 0x78) iff parity(b4,b5,b6) (i&7)
#pragma unroll
    for (int i = 0; i < 128; ++i)
      if (parc(i & 7) && !(i & 64)) { __half2 t = a[i]; a[i] = a[i ^ 0x78]; a[i ^ 0x78] = t; }

    __half2 c2[7], s2[7], ns2[7];
#pragma unroll
    for (int k = 0; k < 7; ++k) {
      float sv, cv; __sincosf(0.5f * wD[d * 7 + k], &sv, &cv);
      c2[k] = __floats2half2_rn(cv, cv);
      s2[k] = __floats2half2_rn(sv, sv);
      ns2[k] = __floats2half2_rn(-sv, -sv);
    }
    ry_sweep<7, 0>(a, c2, s2, ns2);

    // l->t block == flip q4..q6 (mask 7) iff parity(b0..b3) (i&0x78)
#pragma unroll
    for (int i = 0; i < 128; ++i)
      if (parc(i & 0x78) && !(i & 4)) { __half2 t = a[i]; a[i] = a[i ^ 7]; a[i ^ 7] = t; }
  }

  float cls[8];
#pragma unroll
  for (int c = 0; c < 8; ++c) cls[c] = 0.f;
#pragma unroll
  for (int i = 0; i < 128; ++i) cls[i & 7] = ampsq(a[i], cls[i & 7]);
  float z4 = 0.f, z5 = 0.f, z6 = 0.f;
#pragma unroll
  for (int c = 0; c < 8; ++c) {
    z4 += (c & 4) ? -cls[c] : cls[c];
    z5 += (c & 2) ? -cls[c] : cls[c];
    z6 += (c & 1) ? -cls[c] : cls[c];
  }
  z[0] = z4; z[1] = z5; z[2] = z6;
}

// ---------------- fused kernel ----------------------------------------------

__global__ void __launch_bounds__(256, 2)
k_all(const float* __restrict__ x,
      const float* __restrict__ wA, const float* __restrict__ wB,
      const float* __restrict__ wC, const float* __restrict__ wD,
      float* __restrict__ out, int B) {
  const int b = blockIdx.x * blockDim.x + threadIdx.x;
  if (b >= B) return;

  // whole row, coalesced 16B loads (row stride 224B is 16B-aligned)
  float r[56];
  const float4* row4 = (const float4*)(x + (size_t)b * 56);
#pragma unroll
  for (int i = 0; i < 14; ++i) {
    float4 v = row4[i];
    r[4 * i] = v.x; r[4 * i + 1] = v.y; r[4 * i + 2] = v.z; r[4 * i + 3] = v.w;
  }

  float o[9];
  sim4h<0>(r, wA, &o[0]);
  sim4h<1>(r, wB, &o[2]);
  sim4h<2>(r, wC, &o[4]);
  sim7h(r, wD, &o[6]);

  float* op = out + (size_t)b * 9;
#pragma unroll
  for (int i = 0; i < 9; ++i) op[i] = o[i];
}

// ---------------- launch ----------------------------------------------------

extern "C" void kernel_launch(void* const* d_in, const int* in_sizes, int n_in,
                              void* d_out, int out_size, void* d_ws, size_t ws_size,
                              hipStream_t stream) {
  const float* x  = (const float*)d_in[0];
  const float* wA = (const float*)d_in[1];
  const float* wB = (const float*)d_in[2];
  const float* wC = (const float*)d_in[3];
  const float* wD = (const float*)d_in[4];
  float* out = (float*)d_out;
  const int B = in_sizes[0] / 56;
  const int threads = 256;
  const int grid = (B + threads - 1) / threads;
  k_all<<<grid, threads, 0, stream>>>(x, wA, wB, wC, wD, out, B);
}